// Round 10
// baseline (184.305 us; speedup 1.0000x reference)
//
#include <hip/hip_runtime.h>

#define NSEQ   16
#define KVH    8
#define NG     4
#define HD     128
#define BS     16
#define MAXB   256
#define WPT    128    // tokens per item (one wave, 8 phys blocks)
#define NCHUNK 32     // items per (s,kvh)
#define NITEMS (NSEQ * KVH * NCHUNK)   // 4096
#define PSTRIDE 520   // floats per record: o[512], l[4], m, pad
#define REC_BYTES ((size_t)NITEMS * PSTRIDE * 4)
#define SCALE_F 0.08838834764831845f
#define NBLOCKS 1024
#define KVB_BYTES (KVH * HD * BS * 4)   // 64 KiB per phys block per cache

// Kernel 1: wave-level work stealing; every K/V global load is a FULLY
// CONTIGUOUS 1KB instruction (64 lanes x float4). r9 proved this cuts HBM
// FETCH 277->162 MB but spilled (runtime-indexed pointer arrays -> scratch,
// 42 MB/pass). This version is spill-proof: full unrolls (all reg-array
// indices static), no pointer arrays (int bt[8] + uint32 offsets), new-token
// K handled by post-hoc recompute + static cndmask select.
// Lane roles: K(b,o): lane l holds K[d = o*16 + jx][t=(l>>1)&15], jx=(l>>5)*8+(l&1)*4
//   reduce: shfl_xor(1) + shfl_xor(32).
// V(b,sub): lane l holds V[d=sub*16+(l>>2)][tq=(l&3)*4..+4]; reduce xor(1)+xor(2).
__global__ __launch_bounds__(256) void pa_partial_kernel(
    const float* __restrict__ query,
    const float* __restrict__ key,
    const float* __restrict__ value,
    const float* __restrict__ key_cache,
    const float* __restrict__ value_cache,
    const int*   __restrict__ block_tables,
    const int*   __restrict__ context_lens,
    float*       __restrict__ ws,
    unsigned int* __restrict__ counter)
{
    __shared__ float q_all[4][NG * HD];   // per-wave Q
    __shared__ float p_all[4][NG * WPT];  // per-wave probabilities

    const int tid  = threadIdx.x;
    const int wv   = tid >> 6;
    const int lane = tid & 63;
    float* qw = q_all[wv];
    float* pw = p_all[wv];

    const int t_me = (lane >> 1) & 15;           // K-phase token within block
    const int jx   = ((lane >> 5) * 8) + ((lane & 1) * 4);  // K-phase d-offset in o-tile

    const char* kcb = (const char*)key_cache;
    const char* vcb = (const char*)value_cache;

    for (;;) {
        int item;
        if (lane == 0) item = (int)atomicAdd(counter, 1u);
        item = __shfl(item, 0);
        if (item >= NITEMS) return;

        const int ck  = item & (NCHUNK - 1);
        const int kvh = (item >> 5) & (KVH - 1);
        const int s   = item >> 8;
        const int ctx = context_lens[s];
        const int t0  = ck * WPT;
        if (t0 >= ctx) continue;

        const unsigned kvo = (unsigned)kvh * (HD * BS * 4);  // byte offset of kv head

        // ---- stage Q into this wave's LDS slice (wave-local, no barrier) ----
        const float* qsrc = query + (size_t)s * (KVH * NG * HD) + (size_t)kvh * (NG * HD);
        *(float4*)&qw[lane * 8]     = *(const float4*)(qsrc + lane * 8);
        *(float4*)&qw[lane * 8 + 4] = *(const float4*)(qsrc + lane * 8 + 4);

        // ---- block table entries (ints only; addresses computed inline) ----
        int bt[8];
        #pragma unroll
        for (int b = 0; b < 8; ++b)
            bt[b] = block_tables[s * MAXB + (t0 >> 4) + b];

        // ---- QK: 64 contiguous 1KB loads, partial dots ----
        float sc[NG][8];
        #pragma unroll
        for (int g = 0; g < NG; ++g)
            #pragma unroll
            for (int b = 0; b < 8; ++b) sc[g][b] = 0.f;

        #pragma unroll
        for (int o = 0; o < 8; ++o) {
            float4 q4[NG];
            #pragma unroll
            for (int g = 0; g < NG; ++g)
                q4[g] = *(const float4*)&qw[g * HD + o * 16 + jx];
            #pragma unroll
            for (int b = 0; b < 8; ++b) {
                const float4 k4 = *(const float4*)(kcb + (unsigned)bt[b] * KVB_BYTES
                                                   + kvo + lane * 16 + o * 1024);
                #pragma unroll
                for (int g = 0; g < NG; ++g)
                    sc[g][b] += q4[g].x * k4.x + q4[g].y * k4.y
                              + q4[g].z * k4.z + q4[g].w * k4.w;
            }
        }

        // ---- new-token K: recompute affected lanes' partials from `key` ----
        const int tln = ctx - 1 - t0;
        const bool myl = (tln >= 0) && (tln < WPT) && (t_me == (tln & 15));
        if (__any(myl)) {
            float ns[NG] = {0.f, 0.f, 0.f, 0.f};
            const float* keyl = key + ((size_t)s * KVH + kvh) * HD + jx;
            #pragma unroll
            for (int o = 0; o < 8; ++o) {
                const float4 k4 = *(const float4*)(keyl + o * 16);
                #pragma unroll
                for (int g = 0; g < NG; ++g) {
                    const float4 q4 = *(const float4*)&qw[g * HD + o * 16 + jx];
                    ns[g] += q4.x * k4.x + q4.y * k4.y + q4.z * k4.z + q4.w * k4.w;
                }
            }
            #pragma unroll
            for (int b = 0; b < 8; ++b) {
                const bool hit = myl && ((tln >> 4) == b);
                #pragma unroll
                for (int g = 0; g < NG; ++g)
                    sc[g][b] = hit ? ns[g] : sc[g][b];
            }
        }

        // ---- reduce partials (xor1: x-half, xor32: j-half), mask, max ----
        float mv = -1e30f;
        #pragma unroll
        for (int b = 0; b < 8; ++b) {
            const bool act = (t0 + b * 16 + t_me) < ctx;
            #pragma unroll
            for (int g = 0; g < NG; ++g) {
                float v = sc[g][b];
                v += __shfl_xor(v, 1);
                v += __shfl_xor(v, 32);
                v = act ? v * SCALE_F : -1e30f;
                sc[g][b] = v;
                mv = fmaxf(mv, v);
            }
        }
        #pragma unroll
        for (int o2 = 32; o2; o2 >>= 1) mv = fmaxf(mv, __shfl_xor(mv, o2));

        // ---- exp + l; stash p in LDS (16 canonical lanes write) ----
        float l_lane[NG] = {0.f, 0.f, 0.f, 0.f};
        #pragma unroll
        for (int b = 0; b < 8; ++b)
            #pragma unroll
            for (int g = 0; g < NG; ++g) {
                const float pr = __expf(sc[g][b] - mv);   // 0 for masked
                sc[g][b] = pr;
                l_lane[g] += pr;
            }
        if ((lane & 33) == 0) {               // bit0=0,bit5=0: one lane per token
            const int t = lane >> 1;
            #pragma unroll
            for (int g = 0; g < NG; ++g)
                #pragma unroll
                for (int b = 0; b < 8; ++b)
                    pw[g * WPT + b * 16 + t] = sc[g][b];
        }
        #pragma unroll
        for (int o2 = 32; o2; o2 >>= 1) {
            l_lane[0] += __shfl_xor(l_lane[0], o2);
            l_lane[1] += __shfl_xor(l_lane[1], o2);
            l_lane[2] += __shfl_xor(l_lane[2], o2);
            l_lane[3] += __shfl_xor(l_lane[3], o2);
        }   // 4x true sum (each token lives on 4 lanes)

        // ---- PV: 64 contiguous 1KB loads; p4 broadcast from LDS ----
        float acc[NG][8];
        #pragma unroll
        for (int g = 0; g < NG; ++g)
            #pragma unroll
            for (int sub = 0; sub < 8; ++sub) acc[g][sub] = 0.f;

        #pragma unroll
        for (int b = 0; b < 8; ++b) {
            float4 p4[NG];
            #pragma unroll
            for (int g = 0; g < NG; ++g)
                p4[g] = *(const float4*)&pw[g * WPT + b * 16 + (lane & 3) * 4];
            const unsigned vboff = (unsigned)bt[b] * KVB_BYTES + kvo + lane * 16;
            const int tlb = ctx - 1 - t0 - b * 16;
            if (tlb >= 0 && tlb < 16) {       // wave-uniform: new-token block
                const bool myq = (lane & 3) == (tlb >> 2);
                #pragma unroll
                for (int sub = 0; sub < 8; ++sub) {
                    float4 v4 = *(const float4*)(vcb + vboff + sub * 1024);
                    const float vnew = value[((size_t)s * KVH + kvh) * HD
                                             + sub * 16 + (lane >> 2)];
                    v4.x = (myq && (tlb & 3) == 0) ? vnew : v4.x;
                    v4.y = (myq && (tlb & 3) == 1) ? vnew : v4.y;
                    v4.z = (myq && (tlb & 3) == 2) ? vnew : v4.z;
                    v4.w = (myq && (tlb & 3) == 3) ? vnew : v4.w;
                    #pragma unroll
                    for (int g = 0; g < NG; ++g)
                        acc[g][sub] += p4[g].x * v4.x + p4[g].y * v4.y
                                     + p4[g].z * v4.z + p4[g].w * v4.w;
                }
            } else {
                #pragma unroll
                for (int sub = 0; sub < 8; ++sub) {
                    const float4 v4 = *(const float4*)(vcb + vboff + sub * 1024);
                    #pragma unroll
                    for (int g = 0; g < NG; ++g)
                        acc[g][sub] += p4[g].x * v4.x + p4[g].y * v4.y
                                     + p4[g].z * v4.z + p4[g].w * v4.w;
                }
            }
        }

        // ---- reduce token-quads (xor1 + xor2), write record ----
        #pragma unroll
        for (int g = 0; g < NG; ++g)
            #pragma unroll
            for (int sub = 0; sub < 8; ++sub) {
                float a = acc[g][sub];
                a += __shfl_xor(a, 1);
                a += __shfl_xor(a, 2);
                acc[g][sub] = a;
            }

        float* rec = ws + (size_t)item * PSTRIDE;
        if ((lane & 3) == 0) {
            const int dd = lane >> 2;         // 0..15
            #pragma unroll
            for (int g = 0; g < NG; ++g)
                #pragma unroll
                for (int sub = 0; sub < 8; ++sub)
                    rec[g * HD + sub * 16 + dd] = acc[g][sub];
        }
        if (lane == 0) {
            #pragma unroll
            for (int g = 0; g < NG; ++g) rec[512 + g] = l_lane[g] * 0.25f;
            rec[516] = mv;
        }
    }
}

// Kernel 2: LSE-combine the <=32 partitions -> output. One (seq,kvh,g) per block.
__global__ __launch_bounds__(128) void pa_reduce_kernel(
    const float* __restrict__ ws,
    const int*   __restrict__ context_lens,
    float*       __restrict__ out)
{
    const int b    = blockIdx.x;        // ((s*KVH)+kvh)*NG + g
    const int g    = b & 3;
    const int pair = b >> 2;            // s*KVH + kvh
    const int s    = pair >> 3;
    const int kvh  = pair & 7;
    const int ctx  = context_lens[s];
    const int np   = (ctx + WPT - 1) / WPT;

    const int d = threadIdx.x;
    const float* base = ws + (size_t)pair * NCHUNK * PSTRIDE;

    float M = -1e30f;
    for (int p2 = 0; p2 < np; ++p2) M = fmaxf(M, base[p2 * PSTRIDE + 516]);

    float L = 0.f, acc = 0.f;
    for (int p2 = 0; p2 < np; ++p2) {
        const float* rec = base + p2 * PSTRIDE;
        const float w = __expf(rec[516] - M);
        L   += w * rec[512 + g];
        acc += w * rec[g * HD + d];
    }

    out[(size_t)s * (KVH * NG * HD) + (size_t)(kvh * NG + g) * HD + d] = acc / L;
}

extern "C" void kernel_launch(void* const* d_in, const int* in_sizes, int n_in,
                              void* d_out, int out_size, void* d_ws, size_t ws_size,
                              hipStream_t stream) {
    const float* query       = (const float*)d_in[0];
    const float* key         = (const float*)d_in[1];
    const float* value       = (const float*)d_in[2];
    const float* key_cache   = (const float*)d_in[3];
    const float* value_cache = (const float*)d_in[4];
    const int*   block_tables  = (const int*)d_in[5];
    const int*   context_lens  = (const int*)d_in[6];
    // d_in[7] slot_mapping unused: slot is derivable from context_lens + block_tables

    float* out = (float*)d_out;
    float* ws  = (float*)d_ws;   // records: 4096*520*4 = 8.52 MB, + 4 B counter
    unsigned int* counter = (unsigned int*)((char*)d_ws + REC_BYTES);

    hipMemsetAsync(counter, 0, sizeof(unsigned int), stream);
    pa_partial_kernel<<<NBLOCKS, 256, 0, stream>>>(
        query, key, value, key_cache, value_cache, block_tables, context_lens, ws, counter);
    pa_reduce_kernel<<<NSEQ * KVH * NG, 128, 0, stream>>>(ws, context_lens, out);
}

// Round 11
// 150.127 us; speedup vs baseline: 1.2277x; 1.2277x over previous
//
#include <hip/hip_runtime.h>

#define NSEQ   16
#define KVH    8
#define NG     4
#define HD     128
#define BS     16
#define MAXB   256
#define WPT    128    // tokens per item (one wave, 8 phys blocks, online softmax)
#define NCHUNK 32     // items per (s,kvh)
#define NITEMS (NSEQ * KVH * NCHUNK)   // 4096
#define PSTRIDE 520   // floats per record: o[512], l[4], m, pad
#define REC_BYTES ((size_t)NITEMS * PSTRIDE * 4)
#define SCALE_F 0.08838834764831845f
#define NBLOCKS 512   // 2 blocks/CU (LDS-capped), 8 waves/CU
#define KVB_BYTES (KVH * HD * BS * 4)   // 64 KiB per phys block per cache

// async global->LDS, 16B per lane, 1KB per wave-instruction, ZERO VGPR cost.
__device__ __forceinline__ void gload_lds16(const void* g, void* l) {
    __builtin_amdgcn_global_load_lds(
        (const __attribute__((address_space(1))) unsigned int*)g,
        (__attribute__((address_space(3))) unsigned int*)l, 16, 0, 0);
}

// Kernel 1: wave-steals 128-token items; per 16-tok block b: prefetch K(b+1)
// to regs (dbuf) + V(b+1) to LDS via global_load_lds DMA, then QK/online-
// softmax/PV on block b. Counted vmcnt(16) before PV keeps the next block's
// 16KB in flight across the whole compute phase (vmcnt(0) only at b=7).
// Rationale: r3-r10 showed ~4 TB/s wall from in-flight-bytes duty cycle;
// registers can't hold the pipeline (r5/r8/r10 spills/occupancy); LDS-DMA
// holds it for free. Lane algebra = r10's validated contiguous mapping.
__global__ __launch_bounds__(256) void pa_partial_kernel(
    const float* __restrict__ query,
    const float* __restrict__ key,
    const float* __restrict__ value,
    const float* __restrict__ key_cache,
    const float* __restrict__ value_cache,
    const int*   __restrict__ block_tables,
    const int*   __restrict__ context_lens,
    float*       __restrict__ ws,
    unsigned int* __restrict__ counter)
{
    __shared__ __align__(16) float vbuf[4][2][2048];  // per-wave V dbuf (2x8KB)
    __shared__ __align__(16) float qw_all[4][NG * HD];
    __shared__ __align__(16) float pw_all[4][NG * 16];

    const int tid  = threadIdx.x;
    const int wv   = tid >> 6;
    const int lane = tid & 63;
    float* qw  = qw_all[wv];
    float* pww = pw_all[wv];

    const int t_me = (lane >> 1) & 15;                       // K-phase token in block
    const int jx   = ((lane >> 5) * 8) + ((lane & 1) * 4);   // K-phase d-offset in o-tile
    const char* kcb = (const char*)key_cache;
    const char* vcb = (const char*)value_cache;

    for (;;) {
        int item;
        if (lane == 0) item = (int)atomicAdd(counter, 1u);
        item = __shfl(item, 0);
        if (item >= NITEMS) return;

        const int ck  = item & (NCHUNK - 1);
        const int kvh = (item >> 5) & (KVH - 1);
        const int s   = item >> 8;
        const int ctx = context_lens[s];
        const int t0  = ck * WPT;
        if (t0 >= ctx) continue;

        const unsigned kvo = (unsigned)kvh * (HD * BS * 4);

        // stage Q (wave-local LDS; reused across all 8 blocks)
        const float* qsrc = query + (size_t)s * (KVH * NG * HD) + (size_t)kvh * (NG * HD);
        *(float4*)&qw[lane * 8]     = *(const float4*)(qsrc + lane * 8);
        *(float4*)&qw[lane * 8 + 4] = *(const float4*)(qsrc + lane * 8 + 4);

        int bt[8];
        #pragma unroll
        for (int b = 0; b < 8; ++b)
            bt[b] = block_tables[s * MAXB + (t0 >> 4) + b];  // in-bounds always

        // prologue: K(0) -> kreg[0], V(0) DMA -> vbuf[wv][0]
        float4 kreg[2][8];
        {
            const unsigned ko = (unsigned)bt[0] * KVB_BYTES + kvo;
            #pragma unroll
            for (int o = 0; o < 8; ++o)
                kreg[0][o] = *(const float4*)(kcb + ko + (unsigned)lane * 16 + o * 1024);
            #pragma unroll
            for (int sub = 0; sub < 8; ++sub)
                gload_lds16(vcb + ko + sub * 1024 + (unsigned)lane * 16,
                            &vbuf[wv][0][sub * 256]);
        }

        float m = -1e30f;
        float l[NG] = {0.f, 0.f, 0.f, 0.f};
        float acc[NG][8];
        #pragma unroll
        for (int g = 0; g < NG; ++g)
            #pragma unroll
            for (int u = 0; u < 8; ++u) acc[g][u] = 0.f;

        const int tln = ctx - 1 - t0;

        #pragma unroll
        for (int b = 0; b < 8; ++b) {
            // ---- prefetch block b+1 (K->regs, V->LDS DMA): 16KB in flight ----
            if (b < 7) {
                const unsigned ko = (unsigned)bt[b + 1] * KVB_BYTES + kvo;
                #pragma unroll
                for (int o = 0; o < 8; ++o)
                    kreg[(b + 1) & 1][o] =
                        *(const float4*)(kcb + ko + (unsigned)lane * 16 + o * 1024);
                #pragma unroll
                for (int sub = 0; sub < 8; ++sub)
                    gload_lds16(vcb + ko + sub * 1024 + (unsigned)lane * 16,
                                &vbuf[wv][(b + 1) & 1][sub * 256]);
            }
            __builtin_amdgcn_sched_barrier(0);   // pin issues above the compute

            // ---- QK(b) from kreg (compiler-counted wait leaves prefetch flying) ----
            float sc[NG] = {0.f, 0.f, 0.f, 0.f};
            #pragma unroll
            for (int o = 0; o < 8; ++o) {
                const float4 k4 = kreg[b & 1][o];
                #pragma unroll
                for (int g = 0; g < NG; ++g) {
                    const float4 q4 = *(const float4*)&qw[g * HD + o * 16 + jx];
                    sc[g] += q4.x * k4.x + q4.y * k4.y + q4.z * k4.z + q4.w * k4.w;
                }
            }
            // new-token K: token ctx-1's key comes from the `key` input
            const int tlb = tln - b * 16;
            if (tlb >= 0 && tlb < 16) {
                const bool myl = (t_me == tlb);
                float ns[NG] = {0.f, 0.f, 0.f, 0.f};
                const float* keyl = key + ((size_t)s * KVH + kvh) * HD + jx;
                #pragma unroll
                for (int o = 0; o < 8; ++o) {
                    const float4 k4 = *(const float4*)(keyl + o * 16);
                    #pragma unroll
                    for (int g = 0; g < NG; ++g) {
                        const float4 q4 = *(const float4*)&qw[g * HD + o * 16 + jx];
                        ns[g] += q4.x * k4.x + q4.y * k4.y + q4.z * k4.z + q4.w * k4.w;
                    }
                }
                #pragma unroll
                for (int g = 0; g < NG; ++g) sc[g] = myl ? ns[g] : sc[g];
            }

            // ---- reduce (xor1: x-half, xor32: j-half), mask, block max ----
            const bool act = (t0 + b * 16 + t_me) < ctx;
            float mb = -1e30f;
            #pragma unroll
            for (int g = 0; g < NG; ++g) {
                float v = sc[g];
                v += __shfl_xor(v, 1);
                v += __shfl_xor(v, 32);
                v = act ? v * SCALE_F : -1e30f;
                sc[g] = v;
                mb = fmaxf(mb, v);
            }
            #pragma unroll
            for (int o2 = 32; o2; o2 >>= 1) mb = fmaxf(mb, __shfl_xor(mb, o2));

            // ---- online softmax update ----
            const float mnew  = fmaxf(m, mb);
            const float scale = __expf(m - mnew);   // b=0: exp(-inf)=0 zeroes l,acc
            m = mnew;

            float lsum[NG];
            #pragma unroll
            for (int g = 0; g < NG; ++g) {
                const float pr = __expf(sc[g] - mnew);   // 0 for masked
                if ((lane & 33) == 0) pww[g * 16 + (lane >> 1)] = pr;
                lsum[g] = pr;
            }
            #pragma unroll
            for (int o2 = 32; o2; o2 >>= 1) {
                lsum[0] += __shfl_xor(lsum[0], o2);
                lsum[1] += __shfl_xor(lsum[1], o2);
                lsum[2] += __shfl_xor(lsum[2], o2);
                lsum[3] += __shfl_xor(lsum[3], o2);
            }
            #pragma unroll
            for (int g = 0; g < NG; ++g) l[g] = l[g] * scale + lsum[g] * 0.25f;
            #pragma unroll
            for (int g = 0; g < NG; ++g)
                #pragma unroll
                for (int sub = 0; sub < 8; ++sub) acc[g][sub] *= scale;

            // ---- wait V(b) DMA only (counted: prefetch b+1 stays in flight) ----
            if (b < 7) asm volatile("s_waitcnt vmcnt(16)" ::: "memory");
            else       asm volatile("s_waitcnt vmcnt(0)"  ::: "memory");
            __builtin_amdgcn_sched_barrier(0);

            // ---- PV(b) from LDS: lane holds V[d=sub*16+(l>>2)][t4=(l&3)*4..+3] ----
            const float* vb = &vbuf[wv][b & 1][0];
            float4 p4[NG];
            #pragma unroll
            for (int g = 0; g < NG; ++g)
                p4[g] = *(const float4*)&pww[g * 16 + (lane & 3) * 4];

            if (tlb >= 0 && tlb < 16) {   // new-token V: replace stale element
                const bool myq = (lane & 3) == (tlb >> 2);
                #pragma unroll
                for (int sub = 0; sub < 8; ++sub) {
                    float4 v4 = *(const float4*)&vb[sub * 256 + lane * 4];
                    const float vnew = value[((size_t)s * KVH + kvh) * HD
                                             + sub * 16 + (lane >> 2)];
                    v4.x = (myq && (tlb & 3) == 0) ? vnew : v4.x;
                    v4.y = (myq && (tlb & 3) == 1) ? vnew : v4.y;
                    v4.z = (myq && (tlb & 3) == 2) ? vnew : v4.z;
                    v4.w = (myq && (tlb & 3) == 3) ? vnew : v4.w;
                    #pragma unroll
                    for (int g = 0; g < NG; ++g)
                        acc[g][sub] += p4[g].x * v4.x + p4[g].y * v4.y
                                     + p4[g].z * v4.z + p4[g].w * v4.w;
                }
            } else {
                #pragma unroll
                for (int sub = 0; sub < 8; ++sub) {
                    const float4 v4 = *(const float4*)&vb[sub * 256 + lane * 4];
                    #pragma unroll
                    for (int g = 0; g < NG; ++g)
                        acc[g][sub] += p4[g].x * v4.x + p4[g].y * v4.y
                                     + p4[g].z * v4.z + p4[g].w * v4.w;
                }
            }
        }

        // ---- reduce token-quads (xor1+xor2), write record ----
        #pragma unroll
        for (int g = 0; g < NG; ++g)
            #pragma unroll
            for (int sub = 0; sub < 8; ++sub) {
                float a = acc[g][sub];
                a += __shfl_xor(a, 1);
                a += __shfl_xor(a, 2);
                acc[g][sub] = a;
            }

        float* rec = ws + (size_t)item * PSTRIDE;
        if ((lane & 3) == 0) {
            const int dd = lane >> 2;
            #pragma unroll
            for (int g = 0; g < NG; ++g)
                #pragma unroll
                for (int sub = 0; sub < 8; ++sub)
                    rec[g * HD + sub * 16 + dd] = acc[g][sub];
        }
        if (lane == 0) {
            #pragma unroll
            for (int g = 0; g < NG; ++g) rec[512 + g] = l[g];
            rec[516] = m;
        }
    }
}

// Kernel 2: LSE-combine the <=32 partitions -> output. One (seq,kvh,g) per block.
__global__ __launch_bounds__(128) void pa_reduce_kernel(
    const float* __restrict__ ws,
    const int*   __restrict__ context_lens,
    float*       __restrict__ out)
{
    const int b    = blockIdx.x;        // ((s*KVH)+kvh)*NG + g
    const int g    = b & 3;
    const int pair = b >> 2;            // s*KVH + kvh
    const int s    = pair >> 3;
    const int kvh  = pair & 7;
    const int ctx  = context_lens[s];
    const int np   = (ctx + WPT - 1) / WPT;

    const int d = threadIdx.x;
    const float* base = ws + (size_t)pair * NCHUNK * PSTRIDE;

    float M = -1e30f;
    for (int p2 = 0; p2 < np; ++p2) M = fmaxf(M, base[p2 * PSTRIDE + 516]);

    float L = 0.f, acc = 0.f;
    for (int p2 = 0; p2 < np; ++p2) {
        const float* rec = base + p2 * PSTRIDE;
        const float w = __expf(rec[516] - M);
        L   += w * rec[512 + g];
        acc += w * rec[g * HD + d];
    }

    out[(size_t)s * (KVH * NG * HD) + (size_t)(kvh * NG + g) * HD + d] = acc / L;
}

extern "C" void kernel_launch(void* const* d_in, const int* in_sizes, int n_in,
                              void* d_out, int out_size, void* d_ws, size_t ws_size,
                              hipStream_t stream) {
    const float* query       = (const float*)d_in[0];
    const float* key         = (const float*)d_in[1];
    const float* value       = (const float*)d_in[2];
    const float* key_cache   = (const float*)d_in[3];
    const float* value_cache = (const float*)d_in[4];
    const int*   block_tables  = (const int*)d_in[5];
    const int*   context_lens  = (const int*)d_in[6];
    // d_in[7] slot_mapping unused: slot is derivable from context_lens + block_tables

    float* out = (float*)d_out;
    float* ws  = (float*)d_ws;   // records: 4096*520*4 = 8.52 MB, + 4 B counter
    unsigned int* counter = (unsigned int*)((char*)d_ws + REC_BYTES);

    hipMemsetAsync(counter, 0, sizeof(unsigned int), stream);
    pa_partial_kernel<<<NBLOCKS, 256, 0, stream>>>(
        query, key, value, key_cache, value_cache, block_tables, context_lens, ws, counter);
    pa_reduce_kernel<<<NSEQ * KVH * NG, 128, 0, stream>>>(ws, context_lens, out);
}

// Round 12
// 140.377 us; speedup vs baseline: 1.3129x; 1.0695x over previous
//
#include <hip/hip_runtime.h>

#define NSEQ   16
#define KVH    8
#define NG     4
#define HD     128
#define BS     16
#define MAXB   256
#define WPT    128    // tokens per item (one wave, 8 phys blocks)
#define NCHUNK 32     // items per (s,kvh)
#define NITEMS (NSEQ * KVH * NCHUNK)   // 4096
#define PSTRIDE 520   // floats per record: o[512], l[4], m, pad
#define REC_BYTES ((size_t)NITEMS * PSTRIDE * 4)
#define SCALE_F 0.08838834764831845f
#define NBLOCKS 512   // LDS-capped 2 blocks/CU -> full chip at 512
#define KVB_BYTES (KVH * HD * BS * 4)   // 64 KiB per phys block per cache

// async global->LDS: 16B/lane, 1KB/wave-instr, zero VGPR for the payload.
__device__ __forceinline__ void gload_lds16(const void* g, void* l) {
    __builtin_amdgcn_global_load_lds(
        (const __attribute__((address_space(1))) unsigned int*)g,
        (__attribute__((address_space(3))) unsigned int*)l, 16, 0, 0);
}

// Kernel 1: wave-steals 128-token items. Schedule respects vmcnt FIFO:
//   [bulk QK: 64 contiguous 1KB K loads, compiler-pipelined]  (r10 algebra)
//   [issue V0,V1 DMA -> LDS]  [softmax covers V0 latency]
//   [PV loop: wait vmcnt(8) (V(b) in, V(b+1) flying), compute from LDS,
//    issue V(b+2); vmcnt(0) only at b=7]                      (r11 mechanics)
// No kreg dbuf (r11's 64-VGPR mistake), V payload entirely in LDS.
// LDS 80KB -> 2 blocks/CU: occupancy immune to VGPR<=256; only spill matters.
__global__ __launch_bounds__(256) void pa_partial_kernel(
    const float* __restrict__ query,
    const float* __restrict__ key,
    const float* __restrict__ value,
    const float* __restrict__ key_cache,
    const float* __restrict__ value_cache,
    const int*   __restrict__ block_tables,
    const int*   __restrict__ context_lens,
    float*       __restrict__ ws,
    unsigned int* __restrict__ counter)
{
    __shared__ __align__(16) float vbuf[4][2][2048];   // per-wave V dbuf (2x8KB)
    __shared__ __align__(16) float qw_all[4][NG * HD]; // per-wave Q (2KB)
    __shared__ __align__(16) float pw_all[4][NG * WPT];// per-wave p (2KB)

    const int tid  = threadIdx.x;
    const int wv   = tid >> 6;
    const int lane = tid & 63;
    float* qw  = qw_all[wv];
    float* pww = pw_all[wv];

    const int t_me = (lane >> 1) & 15;                      // K-phase token in block
    const int jx   = ((lane >> 5) * 8) + ((lane & 1) * 4);  // K-phase d-offset
    const char* kcb = (const char*)key_cache;
    const char* vcb = (const char*)value_cache;

    for (;;) {
        int item;
        if (lane == 0) item = (int)atomicAdd(counter, 1u);
        item = __shfl(item, 0);
        if (item >= NITEMS) return;

        const int ck  = item & (NCHUNK - 1);
        const int kvh = (item >> 5) & (KVH - 1);
        const int s   = item >> 8;
        const int ctx = context_lens[s];
        const int t0  = ck * WPT;
        if (t0 >= ctx) continue;

        const unsigned kvo = (unsigned)kvh * (HD * BS * 4);

        // ---- stage Q (wave-local; reused all 8 blocks x 4 heads) ----
        const float* qsrc = query + (size_t)s * (KVH * NG * HD) + (size_t)kvh * (NG * HD);
        *(float4*)&qw[lane * 8]     = *(const float4*)(qsrc + lane * 8);
        *(float4*)&qw[lane * 8 + 4] = *(const float4*)(qsrc + lane * 8 + 4);

        int bt[8];
        #pragma unroll
        for (int b = 0; b < 8; ++b)
            bt[b] = block_tables[s * MAXB + (t0 >> 4) + b];   // in-bounds always

        // ---- bulk QK: 64 contiguous 1KB loads (r10 validated algebra) ----
        float sc[NG][8];
        #pragma unroll
        for (int g = 0; g < NG; ++g)
            #pragma unroll
            for (int b = 0; b < 8; ++b) sc[g][b] = 0.f;

        #pragma unroll
        for (int o = 0; o < 8; ++o) {
            float4 q4[NG];
            #pragma unroll
            for (int g = 0; g < NG; ++g)
                q4[g] = *(const float4*)&qw[g * HD + o * 16 + jx];
            #pragma unroll
            for (int b = 0; b < 8; ++b) {
                const float4 k4 = *(const float4*)(kcb + (unsigned)bt[b] * KVB_BYTES
                                                   + kvo + (unsigned)lane * 16 + o * 1024);
                #pragma unroll
                for (int g = 0; g < NG; ++g)
                    sc[g][b] += q4[g].x * k4.x + q4[g].y * k4.y
                              + q4[g].z * k4.z + q4[g].w * k4.w;
            }
        }

        // ---- new-token K: recompute from `key` (one lane-set per item) ----
        const int tln = ctx - 1 - t0;
        const bool myl = (tln >= 0) && (tln < WPT) && (t_me == (tln & 15));
        if (__any(myl)) {
            float ns[NG] = {0.f, 0.f, 0.f, 0.f};
            const float* keyl = key + ((size_t)s * KVH + kvh) * HD + jx;
            #pragma unroll
            for (int o = 0; o < 8; ++o) {
                const float4 k4 = *(const float4*)(keyl + o * 16);
                #pragma unroll
                for (int g = 0; g < NG; ++g) {
                    const float4 q4 = *(const float4*)&qw[g * HD + o * 16 + jx];
                    ns[g] += q4.x * k4.x + q4.y * k4.y + q4.z * k4.z + q4.w * k4.w;
                }
            }
            #pragma unroll
            for (int b = 0; b < 8; ++b) {
                const bool hit = myl && ((tln >> 4) == b);
                #pragma unroll
                for (int g = 0; g < NG; ++g)
                    sc[g][b] = hit ? ns[g] : sc[g][b];
            }
        }

        // ---- issue V0,V1 DMA now (K all consumed; these ride under softmax) ----
        {
            const char* v0 = vcb + (unsigned)bt[0] * KVB_BYTES + kvo + (unsigned)lane * 16;
            const char* v1 = vcb + (unsigned)bt[1] * KVB_BYTES + kvo + (unsigned)lane * 16;
            #pragma unroll
            for (int sub = 0; sub < 8; ++sub)
                gload_lds16(v0 + sub * 1024, &vbuf[wv][0][sub * 256]);
            #pragma unroll
            for (int sub = 0; sub < 8; ++sub)
                gload_lds16(v1 + sub * 1024, &vbuf[wv][1][sub * 256]);
        }

        // ---- reduce (xor1 + xor32), mask, max ----
        float mv = -1e30f;
        #pragma unroll
        for (int b = 0; b < 8; ++b) {
            const bool act = (t0 + b * 16 + t_me) < ctx;
            #pragma unroll
            for (int g = 0; g < NG; ++g) {
                float v = sc[g][b];
                v += __shfl_xor(v, 1);
                v += __shfl_xor(v, 32);
                v = act ? v * SCALE_F : -1e30f;
                sc[g][b] = v;
                mv = fmaxf(mv, v);
            }
        }
        #pragma unroll
        for (int o2 = 32; o2; o2 >>= 1) mv = fmaxf(mv, __shfl_xor(mv, o2));

        // ---- exp + l; stash p in LDS ----
        float l_lane[NG] = {0.f, 0.f, 0.f, 0.f};
        #pragma unroll
        for (int b = 0; b < 8; ++b)
            #pragma unroll
            for (int g = 0; g < NG; ++g) {
                const float pr = __expf(sc[g][b] - mv);   // 0 for masked
                sc[g][b] = pr;
                l_lane[g] += pr;
            }
        if ((lane & 33) == 0) {
            const int t = lane >> 1;
            #pragma unroll
            for (int g = 0; g < NG; ++g)
                #pragma unroll
                for (int b = 0; b < 8; ++b)
                    pww[g * WPT + b * 16 + t] = sc[g][b];
        }
        #pragma unroll
        for (int o2 = 32; o2; o2 >>= 1) {
            l_lane[0] += __shfl_xor(l_lane[0], o2);
            l_lane[1] += __shfl_xor(l_lane[1], o2);
            l_lane[2] += __shfl_xor(l_lane[2], o2);
            l_lane[3] += __shfl_xor(l_lane[3], o2);
        }

        // ---- PV loop: counted-vmcnt dbuf pipeline, V from LDS ----
        float acc[NG][8];
        #pragma unroll
        for (int g = 0; g < NG; ++g)
            #pragma unroll
            for (int sub = 0; sub < 8; ++sub) acc[g][sub] = 0.f;

        #pragma unroll
        for (int b = 0; b < 8; ++b) {
            if (b < 7) asm volatile("s_waitcnt vmcnt(8)" ::: "memory");
            else       asm volatile("s_waitcnt vmcnt(0)" ::: "memory");
            __builtin_amdgcn_sched_barrier(0);

            const float* vb = &vbuf[wv][b & 1][0];
            float4 p4[NG];
            #pragma unroll
            for (int g = 0; g < NG; ++g)
                p4[g] = *(const float4*)&pww[g * WPT + b * 16 + (lane & 3) * 4];

            const int tlb = tln - b * 16;
            if (tlb >= 0 && tlb < 16) {   // new-token V: replace stale element
                const bool myq = (lane & 3) == (tlb >> 2);
                #pragma unroll
                for (int sub = 0; sub < 8; ++sub) {
                    float4 v4 = *(const float4*)&vb[sub * 256 + lane * 4];
                    const float vnew = value[((size_t)s * KVH + kvh) * HD
                                             + sub * 16 + (lane >> 2)];
                    v4.x = (myq && (tlb & 3) == 0) ? vnew : v4.x;
                    v4.y = (myq && (tlb & 3) == 1) ? vnew : v4.y;
                    v4.z = (myq && (tlb & 3) == 2) ? vnew : v4.z;
                    v4.w = (myq && (tlb & 3) == 3) ? vnew : v4.w;
                    #pragma unroll
                    for (int g = 0; g < NG; ++g)
                        acc[g][sub] += p4[g].x * v4.x + p4[g].y * v4.y
                                     + p4[g].z * v4.z + p4[g].w * v4.w;
                }
            } else {
                #pragma unroll
                for (int sub = 0; sub < 8; ++sub) {
                    const float4 v4 = *(const float4*)&vb[sub * 256 + lane * 4];
                    #pragma unroll
                    for (int g = 0; g < NG; ++g)
                        acc[g][sub] += p4[g].x * v4.x + p4[g].y * v4.y
                                     + p4[g].z * v4.z + p4[g].w * v4.w;
                }
            }

            // refill the buffer just consumed (write-after-read: drain ds reads)
            if (b < 6) {
                asm volatile("s_waitcnt lgkmcnt(0)" ::: "memory");
                const char* vn = vcb + (unsigned)bt[b + 2] * KVB_BYTES + kvo
                               + (unsigned)lane * 16;
                #pragma unroll
                for (int sub = 0; sub < 8; ++sub)
                    gload_lds16(vn + sub * 1024, &vbuf[wv][b & 1][sub * 256]);
            }
        }

        // ---- reduce token-quads (xor1+xor2), write record ----
        #pragma unroll
        for (int g = 0; g < NG; ++g)
            #pragma unroll
            for (int sub = 0; sub < 8; ++sub) {
                float a = acc[g][sub];
                a += __shfl_xor(a, 1);
                a += __shfl_xor(a, 2);
                acc[g][sub] = a;
            }

        float* rec = ws + (size_t)item * PSTRIDE;
        if ((lane & 3) == 0) {
            const int dd = lane >> 2;
            #pragma unroll
            for (int g = 0; g < NG; ++g)
                #pragma unroll
                for (int sub = 0; sub < 8; ++sub)
                    rec[g * HD + sub * 16 + dd] = acc[g][sub];
        }
        if (lane == 0) {
            #pragma unroll
            for (int g = 0; g < NG; ++g) rec[512 + g] = l_lane[g] * 0.25f;
            rec[516] = mv;
        }
    }
}

// Kernel 2: LSE-combine the <=32 partitions -> output. One (seq,kvh,g) per block.
__global__ __launch_bounds__(128) void pa_reduce_kernel(
    const float* __restrict__ ws,
    const int*   __restrict__ context_lens,
    float*       __restrict__ out)
{
    const int b    = blockIdx.x;        // ((s*KVH)+kvh)*NG + g
    const int g    = b & 3;
    const int pair = b >> 2;            // s*KVH + kvh
    const int s    = pair >> 3;
    const int kvh  = pair & 7;
    const int ctx  = context_lens[s];
    const int np   = (ctx + WPT - 1) / WPT;

    const int d = threadIdx.x;
    const float* base = ws + (size_t)pair * NCHUNK * PSTRIDE;

    float M = -1e30f;
    for (int p2 = 0; p2 < np; ++p2) M = fmaxf(M, base[p2 * PSTRIDE + 516]);

    float L = 0.f, acc = 0.f;
    for (int p2 = 0; p2 < np; ++p2) {
        const float* rec = base + p2 * PSTRIDE;
        const float w = __expf(rec[516] - M);
        L   += w * rec[512 + g];
        acc += w * rec[g * HD + d];
    }

    out[(size_t)s * (KVH * NG * HD) + (size_t)(kvh * NG + g) * HD + d] = acc / L;
}

extern "C" void kernel_launch(void* const* d_in, const int* in_sizes, int n_in,
                              void* d_out, int out_size, void* d_ws, size_t ws_size,
                              hipStream_t stream) {
    const float* query       = (const float*)d_in[0];
    const float* key         = (const float*)d_in[1];
    const float* value       = (const float*)d_in[2];
    const float* key_cache   = (const float*)d_in[3];
    const float* value_cache = (const float*)d_in[4];
    const int*   block_tables  = (const int*)d_in[5];
    const int*   context_lens  = (const int*)d_in[6];
    // d_in[7] slot_mapping unused: slot is derivable from context_lens + block_tables

    float* out = (float*)d_out;
    float* ws  = (float*)d_ws;   // records: 4096*520*4 = 8.52 MB, + 4 B counter
    unsigned int* counter = (unsigned int*)((char*)d_ws + REC_BYTES);

    hipMemsetAsync(counter, 0, sizeof(unsigned int), stream);
    pa_partial_kernel<<<NBLOCKS, 256, 0, stream>>>(
        query, key, value, key_cache, value_cache, block_tables, context_lens, ws, counter);
    pa_reduce_kernel<<<NSEQ * KVH * NG, 128, 0, stream>>>(ws, context_lens, out);
}

// Round 14
// 107.709 us; speedup vs baseline: 1.7111x; 1.3033x over previous
//
#include <hip/hip_runtime.h>

#define NSEQ   16
#define KVH    8
#define NG     4      // query heads per kv head
#define HD     128
#define BS     16
#define MAXB   256
#define PART   256    // tokens per work item (4 waves x 64)
#define NPART  16
#define NITEMS (NSEQ * KVH * NPART)   // 2048 work items
#define WPT    64     // tokens per wave
#define PSTRIDE 520   // floats per partition record: o[512], l[4], m, pad
#define REC_BYTES ((size_t)NITEMS * PSTRIDE * 4)
#define SCALE_F 0.08838834764831845f
#define NWORKERS 1024

// clang native vector (NOT HIP_vector_type): accepted by nontemporal builtins.
typedef float vf4 __attribute__((ext_vector_type(4)));

// Non-temporal 16B load: global_load_dwordx4 with `nt` -> KV stream does not
// allocate/thrash L3. KV has ZERO reuse within a pass (each (block,kvh) read
// by exactly one wave; GQA folded) and 285MB/pass demand vs 256MB L3 means
// normal loads thrash the Infinity Cache -- hypothesized ~4 TB/s wall r3-r12.
__device__ __forceinline__ vf4 ldnt4(const float* p) {
    return __builtin_nontemporal_load((const vf4*)p);
}
__device__ __forceinline__ float ldnt1(const float* p) {
    return __builtin_nontemporal_load(p);
}

// Kernel 1: r7's exact structure (block-level work stealing, two-barrier grab,
// 4 independent waves x 64 tokens, wave-local softmax, single merge barrier).
// ONLY change vs r7: key_cache/value_cache reads are non-temporal.
__global__ __launch_bounds__(256) void pa_partial_kernel(
    const float* __restrict__ query,
    const float* __restrict__ key,
    const float* __restrict__ value,
    const float* __restrict__ key_cache,
    const float* __restrict__ value_cache,
    const int*   __restrict__ block_tables,
    const int*   __restrict__ context_lens,
    float*       __restrict__ ws,
    unsigned int* __restrict__ counter)
{
    __shared__ float p_lds[4][NG][WPT];   // per-wave probabilities
    __shared__ float o_lds[4][NG * HD];   // per-wave partial outputs
    __shared__ float ml_lds[4][8];        // per-wave m, l[4]
    __shared__ int   item_s;

    const int tid  = threadIdx.x;
    const int wv   = tid >> 6;
    const int lane = tid & 63;

    for (;;) {
        if (tid == 0) item_s = (int)atomicAdd(counter, 1u);
        __syncthreads();                  // B1: item_s write visible
        const int item = item_s;
        __syncthreads();                  // B2: all have read; safe to overwrite later
        if (item >= NITEMS) return;

        const int p   = item & (NPART - 1);
        const int kvh = (item >> 4) & (KVH - 1);
        const int s   = item >> 7;
        const int ctx = context_lens[s];
        const int t0  = p * PART;
        if (t0 >= ctx) continue;          // barrier-safe skip

        const int tw0  = t0 + wv * WPT;
        const bool wact = (tw0 < ctx);

        const float* q = query + ((size_t)s * KVH + kvh) * (NG * HD);

        float m_w = -1e30f;
        float l_w[NG] = {0.f, 0.f, 0.f, 0.f};

        if (wact) {
            // ---- QK: one token per lane (nt loads on K cache) ----
            const int t  = tw0 + lane;                     // < 4096: in-bounds
            const int bt = block_tables[s * MAXB + (t >> 4)];
            const float* kb = key_cache + (size_t)bt * (KVH * HD * BS)
                                        + (size_t)kvh * (HD * BS) + (t & 15) * 8;

            float sc[NG] = {0.f, 0.f, 0.f, 0.f};
            #pragma unroll
            for (int j = 0; j < 16; ++j) {
                const vf4 ka = ldnt4(kb + j * 128);
                const vf4 kc = ldnt4(kb + j * 128 + 4);
                #pragma unroll
                for (int g = 0; g < NG; ++g) {
                    sc[g] += q[g * HD + j * 8 + 0] * ka[0] + q[g * HD + j * 8 + 1] * ka[1]
                           + q[g * HD + j * 8 + 2] * ka[2] + q[g * HD + j * 8 + 3] * ka[3]
                           + q[g * HD + j * 8 + 4] * kc[0] + q[g * HD + j * 8 + 5] * kc[1]
                           + q[g * HD + j * 8 + 6] * kc[2] + q[g * HD + j * 8 + 7] * kc[3];
                }
            }

            // new-token K correction: token ctx-1's key comes from the `key` input
            if (t == ctx - 1) {
                const float* kn = key + ((size_t)s * KVH + kvh) * HD;
                float ns[NG] = {0.f, 0.f, 0.f, 0.f};
                #pragma unroll
                for (int c = 0; c < 32; ++c) {
                    const vf4 k4 = *(const vf4*)(kn + c * 4);
                    #pragma unroll
                    for (int g = 0; g < NG; ++g) {
                        ns[g] += q[g * HD + c * 4 + 0] * k4[0] + q[g * HD + c * 4 + 1] * k4[1]
                               + q[g * HD + c * 4 + 2] * k4[2] + q[g * HD + c * 4 + 3] * k4[3];
                    }
                }
                #pragma unroll
                for (int g = 0; g < NG; ++g) sc[g] = ns[g];
            }

            float mv;
            if (t < ctx) {
                #pragma unroll
                for (int g = 0; g < NG; ++g) sc[g] *= SCALE_F;
                mv = fmaxf(fmaxf(sc[0], sc[1]), fmaxf(sc[2], sc[3]));
            } else {
                #pragma unroll
                for (int g = 0; g < NG; ++g) sc[g] = -1e30f;
                mv = -1e30f;
            }

            #pragma unroll
            for (int o = 32; o; o >>= 1) mv = fmaxf(mv, __shfl_xor(mv, o));
            m_w = mv;

            float pr[NG];
            #pragma unroll
            for (int g = 0; g < NG; ++g) {
                pr[g] = __expf(sc[g] - m_w);
                p_lds[wv][g][lane] = pr[g];
                l_w[g] = pr[g];
            }
            #pragma unroll
            for (int o = 32; o; o >>= 1) {
                l_w[0] += __shfl_xor(l_w[0], o);
                l_w[1] += __shfl_xor(l_w[1], o);
                l_w[2] += __shfl_xor(l_w[2], o);
                l_w[3] += __shfl_xor(l_w[3], o);
            }
        }

        if (lane == 0) {
            ml_lds[wv][0] = m_w;
            #pragma unroll
            for (int g = 0; g < NG; ++g) ml_lds[wv][1 + g] = l_w[g];
        }

        // ---- PV: wave-local, lane = d (two halves), nt loads on V cache ----
        if (wact) {
            const int nbv = min(4, (ctx - tw0 + 15) >> 4);
            int btv[4];
            #pragma unroll
            for (int b = 0; b < 4; ++b)
                btv[b] = block_tables[s * MAXB + (tw0 >> 4) + b];  // uniform, in-bounds

            const int tl = ctx - 1 - tw0;
            const float4* pl4 = (const float4*)&p_lds[wv][0][0];

            #pragma unroll 2
            for (int half = 0; half < 2; ++half) {
                const int d = lane + half * 64;
                float a[NG] = {0.f, 0.f, 0.f, 0.f};
                for (int b = 0; b < nbv; ++b) {
                    const float* vb = value_cache + (size_t)btv[b] * (KVH * HD * BS)
                                                  + (size_t)kvh * (HD * BS) + d * BS;
                    #pragma unroll
                    for (int c = 0; c < 4; ++c) {
                        const vf4 v4 = ldnt4(vb + c * 4);
                        #pragma unroll
                        for (int g = 0; g < NG; ++g) {
                            const float4 pg = pl4[g * 16 + b * 4 + c];
                            a[g] += pg.x * v4[0] + pg.y * v4[1] + pg.z * v4[2] + pg.w * v4[3];
                        }
                    }
                }
                if (tl >= 0 && tl < WPT) {
                    const int btn = block_tables[s * MAXB + ((ctx - 1) >> 4)];
                    const float vold = ldnt1(value_cache + (size_t)btn * (KVH * HD * BS)
                                             + (size_t)kvh * (HD * BS) + d * BS + ((ctx - 1) & 15));
                    const float vnew = value[((size_t)s * KVH + kvh) * HD + d];
                    const float dv = vnew - vold;
                    #pragma unroll
                    for (int g = 0; g < NG; ++g) a[g] += p_lds[wv][g][tl] * dv;
                }
                #pragma unroll
                for (int g = 0; g < NG; ++g) o_lds[wv][g * HD + d] = a[g];
            }
        } else {
            #pragma unroll
            for (int i = 0; i < 8; ++i) o_lds[wv][i * 64 + lane] = 0.f;
        }

        __syncthreads();   // merge the 4 wave records

        const float m0 = ml_lds[0][0], m1 = ml_lds[1][0], m2 = ml_lds[2][0], m3 = ml_lds[3][0];
        const float M  = fmaxf(fmaxf(m0, m1), fmaxf(m2, m3));
        const float w0 = __expf(m0 - M), w1 = __expf(m1 - M);
        const float w2 = __expf(m2 - M), w3 = __expf(m3 - M);

        float* rec = ws + (size_t)item * PSTRIDE;
        #pragma unroll
        for (int r = 0; r < 2; ++r) {
            const int idx = tid + r * 256;
            rec[idx] = w0 * o_lds[0][idx] + w1 * o_lds[1][idx]
                     + w2 * o_lds[2][idx] + w3 * o_lds[3][idx];
        }
        if (tid < NG) {
            rec[512 + tid] = w0 * ml_lds[0][1 + tid] + w1 * ml_lds[1][1 + tid]
                           + w2 * ml_lds[2][1 + tid] + w3 * ml_lds[3][1 + tid];
        }
        if (tid == 4) rec[516] = M;
        // next grab's B1 separates this item's o_lds reads from the next item's writes
    }
}

// Kernel 2: LSE-combine partitions -> output. One (seq, kvh, g) per block.
__global__ __launch_bounds__(128) void pa_reduce_kernel(
    const float* __restrict__ ws,
    const int*   __restrict__ context_lens,
    float*       __restrict__ out)
{
    const int b    = blockIdx.x;        // ((s*KVH)+kvh)*NG + g
    const int g    = b & 3;
    const int pair = b >> 2;            // s*KVH + kvh
    const int s    = pair >> 3;
    const int kvh  = pair & 7;
    const int ctx  = context_lens[s];
    const int np   = (ctx + PART - 1) / PART;

    const int d = threadIdx.x;
    const float* base = ws + (size_t)pair * NPART * PSTRIDE;

    float M = -1e30f;
    for (int p2 = 0; p2 < np; ++p2) M = fmaxf(M, base[p2 * PSTRIDE + 516]);

    float L = 0.f, acc = 0.f;
    for (int p2 = 0; p2 < np; ++p2) {
        const float* rec = base + p2 * PSTRIDE;
        const float w = __expf(rec[516] - M);
        L   += w * rec[512 + g];
        acc += w * rec[g * HD + d];
    }

    out[(size_t)s * (KVH * NG * HD) + (size_t)(kvh * NG + g) * HD + d] = acc / L;
}

extern "C" void kernel_launch(void* const* d_in, const int* in_sizes, int n_in,
                              void* d_out, int out_size, void* d_ws, size_t ws_size,
                              hipStream_t stream) {
    const float* query       = (const float*)d_in[0];
    const float* key         = (const float*)d_in[1];
    const float* value       = (const float*)d_in[2];
    const float* key_cache   = (const float*)d_in[3];
    const float* value_cache = (const float*)d_in[4];
    const int*   block_tables  = (const int*)d_in[5];
    const int*   context_lens  = (const int*)d_in[6];
    // d_in[7] slot_mapping unused: slot is derivable from context_lens + block_tables

    float* out = (float*)d_out;
    float* ws  = (float*)d_ws;   // records: 2048*520*4 = 4.26 MB, + 4 B counter
    unsigned int* counter = (unsigned int*)((char*)d_ws + REC_BYTES);

    (void)hipMemsetAsync(counter, 0, sizeof(unsigned int), stream);
    pa_partial_kernel<<<NWORKERS, 256, 0, stream>>>(
        query, key, value, key_cache, value_cache, block_tables, context_lens, ws, counter);
    pa_reduce_kernel<<<NSEQ * KVH * NG, 128, 0, stream>>>(ws, context_lens, out);
}

// Round 15
// 83.602 us; speedup vs baseline: 2.2046x; 1.2884x over previous
//
#include <hip/hip_runtime.h>

#define NSEQ   16
#define KVH    8
#define NG     4      // query heads per kv head
#define HD     128
#define BS     16
#define MAXB   256
#define PART   256    // tokens per work item (4 waves x 64)
#define NPART  16
#define NITEMS (NSEQ * KVH * NPART)   // 2048 work items
#define WPT    64     // tokens per wave
#define PSTRIDE 520   // floats per partition record: o[512], l[4], m, pad
#define REC_BYTES ((size_t)NITEMS * PSTRIDE * 4)
#define SCALE_F 0.08838834764831845f
#define NWORKERS 1024

// Kernel 1: r7's shell (block-level work stealing, two-barrier grab, 4
// independent waves x 64 tokens, wave-local softmax, single merge barrier).
// ONE change vs r7 (85.0us): the PV phase uses CONTIGUOUS 1KB V loads.
//   old: lane=d reads 16B at 64B stride -> 64 line-touches/instr, 4x per line
//   new: instr (b,sub): lane l reads byte l*16 of a 1KB span
//        = V[d=sub*16+(l>>2)][tok (l&3)*4..+3]; p4 via LDS broadcast;
//        reduce xor(1)+xor(2); lanes with (l&3)==0 own d=sub*16+(l>>2).
// Line-touches per wave-item: V 2048 -> 512 (K unchanged at 1024). Theory:
// per-CU line-request service rate is the r3-r14 ~4TB/s wall (r14: nt loads
// raised service latency -> slower; r12: fewer waves -> fewer queue slots ->
// slower; fill kernel: contiguous 1x touches -> 6.9TB/s).
__global__ __launch_bounds__(256) void pa_partial_kernel(
    const float* __restrict__ query,
    const float* __restrict__ key,
    const float* __restrict__ value,
    const float* __restrict__ key_cache,
    const float* __restrict__ value_cache,
    const int*   __restrict__ block_tables,
    const int*   __restrict__ context_lens,
    float*       __restrict__ ws,
    unsigned int* __restrict__ counter)
{
    __shared__ float p_lds[4][NG][WPT];   // per-wave probabilities
    __shared__ float o_lds[4][NG * HD];   // per-wave partial outputs
    __shared__ float ml_lds[4][8];        // per-wave m, l[4]
    __shared__ int   item_s;

    const int tid  = threadIdx.x;
    const int wv   = tid >> 6;
    const int lane = tid & 63;

    for (;;) {
        if (tid == 0) item_s = (int)atomicAdd(counter, 1u);
        __syncthreads();                  // B1: item_s write visible
        const int item = item_s;
        __syncthreads();                  // B2: all have read; safe to overwrite later
        if (item >= NITEMS) return;

        const int p   = item & (NPART - 1);
        const int kvh = (item >> 4) & (KVH - 1);
        const int s   = item >> 7;
        const int ctx = context_lens[s];
        const int t0  = p * PART;
        if (t0 >= ctx) continue;          // barrier-safe skip

        const int tw0  = t0 + wv * WPT;
        const bool wact = (tw0 < ctx);

        const float* q = query + ((size_t)s * KVH + kvh) * (NG * HD);

        float m_w = -1e30f;
        float l_w[NG] = {0.f, 0.f, 0.f, 0.f};

        if (wact) {
            // ---- QK: one token per lane (unchanged from r7) ----
            const int t  = tw0 + lane;                     // < 4096: in-bounds
            const int bt = block_tables[s * MAXB + (t >> 4)];
            const float* kb = key_cache + (size_t)bt * (KVH * HD * BS)
                                        + (size_t)kvh * (HD * BS) + (t & 15) * 8;

            float sc[NG] = {0.f, 0.f, 0.f, 0.f};
            #pragma unroll
            for (int j = 0; j < 16; ++j) {
                const float4 ka = *(const float4*)(kb + j * 128);
                const float4 kc = *(const float4*)(kb + j * 128 + 4);
                #pragma unroll
                for (int g = 0; g < NG; ++g) {
                    sc[g] += q[g * HD + j * 8 + 0] * ka.x + q[g * HD + j * 8 + 1] * ka.y
                           + q[g * HD + j * 8 + 2] * ka.z + q[g * HD + j * 8 + 3] * ka.w
                           + q[g * HD + j * 8 + 4] * kc.x + q[g * HD + j * 8 + 5] * kc.y
                           + q[g * HD + j * 8 + 6] * kc.z + q[g * HD + j * 8 + 7] * kc.w;
                }
            }

            // new-token K correction: token ctx-1's key comes from the `key` input
            if (t == ctx - 1) {
                const float4* kn4 = (const float4*)(key + ((size_t)s * KVH + kvh) * HD);
                float ns[NG] = {0.f, 0.f, 0.f, 0.f};
                #pragma unroll
                for (int c = 0; c < 32; ++c) {
                    const float4 k4 = kn4[c];
                    #pragma unroll
                    for (int g = 0; g < NG; ++g) {
                        ns[g] += q[g * HD + c * 4 + 0] * k4.x + q[g * HD + c * 4 + 1] * k4.y
                               + q[g * HD + c * 4 + 2] * k4.z + q[g * HD + c * 4 + 3] * k4.w;
                    }
                }
                #pragma unroll
                for (int g = 0; g < NG; ++g) sc[g] = ns[g];
            }

            float mv;
            if (t < ctx) {
                #pragma unroll
                for (int g = 0; g < NG; ++g) sc[g] *= SCALE_F;
                mv = fmaxf(fmaxf(sc[0], sc[1]), fmaxf(sc[2], sc[3]));
            } else {
                #pragma unroll
                for (int g = 0; g < NG; ++g) sc[g] = -1e30f;
                mv = -1e30f;
            }

            #pragma unroll
            for (int o = 32; o; o >>= 1) mv = fmaxf(mv, __shfl_xor(mv, o));
            m_w = mv;

            float pr[NG];
            #pragma unroll
            for (int g = 0; g < NG; ++g) {
                pr[g] = __expf(sc[g] - m_w);
                p_lds[wv][g][lane] = pr[g];
                l_w[g] = pr[g];
            }
            #pragma unroll
            for (int o = 32; o; o >>= 1) {
                l_w[0] += __shfl_xor(l_w[0], o);
                l_w[1] += __shfl_xor(l_w[1], o);
                l_w[2] += __shfl_xor(l_w[2], o);
                l_w[3] += __shfl_xor(l_w[3], o);
            }
        }

        if (lane == 0) {
            ml_lds[wv][0] = m_w;
            #pragma unroll
            for (int g = 0; g < NG; ++g) ml_lds[wv][1 + g] = l_w[g];
        }

        // ---- PV: contiguous 1KB V loads (the round-15 change) ----
        if (wact) {
            int btv[4];
            #pragma unroll
            for (int b = 0; b < 4; ++b)
                btv[b] = block_tables[s * MAXB + (tw0 >> 4) + b];  // uniform, in-bounds

            const int tl = ctx - 1 - tw0;
            const int tq = lane & 3;          // token-quad within block
            const int dl = lane >> 2;         // d sub-index 0..15

            float acc[NG][8];
            #pragma unroll
            for (int g = 0; g < NG; ++g)
                #pragma unroll
                for (int sub = 0; sub < 8; ++sub) acc[g][sub] = 0.f;

            #pragma unroll
            for (int b = 0; b < 4; ++b) {
                if (tw0 + b * 16 < ctx) {     // skip fully-masked blocks
                    const float* vb = value_cache + (size_t)btv[b] * (KVH * HD * BS)
                                                  + (size_t)kvh * (HD * BS);
                    float4 p4[NG];
                    #pragma unroll
                    for (int g = 0; g < NG; ++g)
                        p4[g] = *(const float4*)&p_lds[wv][g][b * 16 + tq * 4];
                    #pragma unroll
                    for (int sub = 0; sub < 8; ++sub) {
                        const float4 v4 = *(const float4*)(vb + sub * 256 + lane * 4);
                        #pragma unroll
                        for (int g = 0; g < NG; ++g)
                            acc[g][sub] += p4[g].x * v4.x + p4[g].y * v4.y
                                         + p4[g].z * v4.z + p4[g].w * v4.w;
                    }
                }
            }

            // reduce the 4 token-quad groups
            #pragma unroll
            for (int g = 0; g < NG; ++g)
                #pragma unroll
                for (int sub = 0; sub < 8; ++sub) {
                    float a = acc[g][sub];
                    a += __shfl_xor(a, 1);
                    a += __shfl_xor(a, 2);
                    acc[g][sub] = a;
                }

            // new-token V correction (post-reduce; all 4 copies stay identical)
            if (tl >= 0 && tl < WPT) {
                const int btn = block_tables[s * MAXB + ((ctx - 1) >> 4)];
                const float* vbn = value_cache + (size_t)btn * (KVH * HD * BS)
                                               + (size_t)kvh * (HD * BS) + ((ctx - 1) & 15);
                const float* vrow = value + ((size_t)s * KVH + kvh) * HD;
                #pragma unroll
                for (int sub = 0; sub < 8; ++sub) {
                    const int d = sub * 16 + dl;
                    const float dv = vrow[d] - vbn[d * BS];
                    #pragma unroll
                    for (int g = 0; g < NG; ++g)
                        acc[g][sub] += p_lds[wv][g][tl] * dv;
                }
            }

            if (tq == 0) {
                #pragma unroll
                for (int g = 0; g < NG; ++g)
                    #pragma unroll
                    for (int sub = 0; sub < 8; ++sub)
                        o_lds[wv][g * HD + sub * 16 + dl] = acc[g][sub];
            }
        } else {
            #pragma unroll
            for (int i = 0; i < 8; ++i) o_lds[wv][i * 64 + lane] = 0.f;
        }

        __syncthreads();   // merge the 4 wave records

        const float m0 = ml_lds[0][0], m1 = ml_lds[1][0], m2 = ml_lds[2][0], m3 = ml_lds[3][0];
        const float M  = fmaxf(fmaxf(m0, m1), fmaxf(m2, m3));
        const float w0 = __expf(m0 - M), w1 = __expf(m1 - M);
        const float w2 = __expf(m2 - M), w3 = __expf(m3 - M);

        float* rec = ws + (size_t)item * PSTRIDE;
        #pragma unroll
        for (int r = 0; r < 2; ++r) {
            const int idx = tid + r * 256;
            rec[idx] = w0 * o_lds[0][idx] + w1 * o_lds[1][idx]
                     + w2 * o_lds[2][idx] + w3 * o_lds[3][idx];
        }
        if (tid < NG) {
            rec[512 + tid] = w0 * ml_lds[0][1 + tid] + w1 * ml_lds[1][1 + tid]
                           + w2 * ml_lds[2][1 + tid] + w3 * ml_lds[3][1 + tid];
        }
        if (tid == 4) rec[516] = M;
        // next grab's B1 separates this item's o_lds reads from the next item's writes
    }
}

// Kernel 2: LSE-combine partitions -> output. One (seq, kvh, g) per block.
__global__ __launch_bounds__(128) void pa_reduce_kernel(
    const float* __restrict__ ws,
    const int*   __restrict__ context_lens,
    float*       __restrict__ out)
{
    const int b    = blockIdx.x;        // ((s*KVH)+kvh)*NG + g
    const int g    = b & 3;
    const int pair = b >> 2;            // s*KVH + kvh
    const int s    = pair >> 3;
    const int kvh  = pair & 7;
    const int ctx  = context_lens[s];
    const int np   = (ctx + PART - 1) / PART;

    const int d = threadIdx.x;
    const float* base = ws + (size_t)pair * NPART * PSTRIDE;

    float M = -1e30f;
    for (int p2 = 0; p2 < np; ++p2) M = fmaxf(M, base[p2 * PSTRIDE + 516]);

    float L = 0.f, acc = 0.f;
    for (int p2 = 0; p2 < np; ++p2) {
        const float* rec = base + p2 * PSTRIDE;
        const float w = __expf(rec[516] - M);
        L   += w * rec[512 + g];
        acc += w * rec[g * HD + d];
    }

    out[(size_t)s * (KVH * NG * HD) + (size_t)(kvh * NG + g) * HD + d] = acc / L;
}

extern "C" void kernel_launch(void* const* d_in, const int* in_sizes, int n_in,
                              void* d_out, int out_size, void* d_ws, size_t ws_size,
                              hipStream_t stream) {
    const float* query       = (const float*)d_in[0];
    const float* key         = (const float*)d_in[1];
    const float* value       = (const float*)d_in[2];
    const float* key_cache   = (const float*)d_in[3];
    const float* value_cache = (const float*)d_in[4];
    const int*   block_tables  = (const int*)d_in[5];
    const int*   context_lens  = (const int*)d_in[6];
    // d_in[7] slot_mapping unused: slot is derivable from context_lens + block_tables

    float* out = (float*)d_out;
    float* ws  = (float*)d_ws;   // records: 2048*520*4 = 4.26 MB, + 4 B counter
    unsigned int* counter = (unsigned int*)((char*)d_ws + REC_BYTES);

    (void)hipMemsetAsync(counter, 0, sizeof(unsigned int), stream);
    pa_partial_kernel<<<NWORKERS, 256, 0, stream>>>(
        query, key, value, key_cache, value_cache, block_tables, context_lens, ws, counter);
    pa_reduce_kernel<<<NSEQ * KVH * NG, 128, 0, stream>>>(ws, context_lens, out);
}